// Round 14
// baseline (471.547 us; speedup 1.0000x reference)
//
#include <hip/hip_runtime.h>
#include <hip/hip_bf16.h>
#include <stdint.h>

using bf16x8 = __attribute__((ext_vector_type(8))) __bf16;
using f32x4  = __attribute__((ext_vector_type(4))) float;

__device__ __forceinline__ uint16_t f2bf(float f) {
    uint32_t u = __builtin_bit_cast(uint32_t, f);
    u += 0x7FFFu + ((u >> 16) & 1u);
    return (uint16_t)(u >> 16);
}
__device__ __forceinline__ uint32_t pack2bf(float lo, float hi) {
    return (uint32_t)f2bf(lo) | ((uint32_t)f2bf(hi) << 16);
}

__device__ __forceinline__ void gld_lds16(const void* g, void* l) {
    __builtin_amdgcn_global_load_lds(
        (const __attribute__((address_space(1))) void*)g,
        (__attribute__((address_space(3))) void*)l,
        16, 0, 0);
}

// ------- batched weight convert+transpose: fp32 [R][C] -> bf16 [C][R] -------
__global__ __launch_bounds__(256)
void wconvB(const float* __restrict__ i0, const float* __restrict__ i1,
            const float* __restrict__ i2, uint16_t* __restrict__ o0,
            uint16_t* __restrict__ o1, uint16_t* __restrict__ o2,
            int R, int C) {
    int z = blockIdx.z;
    const float* in = z == 0 ? i0 : (z == 1 ? i1 : i2);
    uint16_t* out   = z == 0 ? o0 : (z == 1 ? o1 : o2);
    __shared__ float t[32][33];
    int c0 = blockIdx.x * 32, r0 = blockIdx.y * 32;
    int tx = threadIdx.x & 31, ty = threadIdx.x >> 5;  // 32 x 8
    #pragma unroll
    for (int i = 0; i < 32; i += 8)
        t[ty + i][tx] = in[(size_t)(r0 + ty + i) * C + c0 + tx];
    __syncthreads();
    #pragma unroll
    for (int i = 0; i < 32; i += 8)
        out[(size_t)(c0 + ty + i) * R + r0 + tx] = f2bf(t[tx][ty + i]);
}

// ---------------- LayerNorm fp32 -> bf16, D = 1024, one row per block -------
__global__ __launch_bounds__(256)
void ln_bf16(const float* __restrict__ x, const float* __restrict__ gw,
             const float* __restrict__ bw, uint16_t* __restrict__ out) {
    const int D = 1024;
    int row = blockIdx.x;
    float4 v = ((const float4*)(x + (size_t)row * D))[threadIdx.x];
    float s  = v.x + v.y + v.z + v.w;
    float ss = v.x * v.x + v.y * v.y + v.z * v.z + v.w * v.w;
    #pragma unroll
    for (int m = 1; m < 64; m <<= 1) {
        s  += __shfl_xor(s, m);
        ss += __shfl_xor(ss, m);
    }
    __shared__ float red[8];
    int wid = threadIdx.x >> 6, lane = threadIdx.x & 63;
    if (lane == 0) { red[wid] = s; red[4 + wid] = ss; }
    __syncthreads();
    s  = red[0] + red[1] + red[2] + red[3];
    ss = red[4] + red[5] + red[6] + red[7];
    float mu  = s * (1.f / 1024.f);
    float var = ss * (1.f / 1024.f) - mu * mu;
    float rstd = rsqrtf(var + 1e-5f);
    float4 gv = ((const float4*)gw)[threadIdx.x];
    float4 bv = ((const float4*)bw)[threadIdx.x];
    ushort4 o;
    o.x = f2bf((v.x - mu) * rstd * gv.x + bv.x);
    o.y = f2bf((v.y - mu) * rstd * gv.y + bv.y);
    o.z = f2bf((v.z - mu) * rstd * gv.z + bv.z);
    o.w = f2bf((v.w - mu) * rstd * gv.w + bv.w);
    ((ushort4*)(out + (size_t)row * D))[threadIdx.x] = o;
}

// ---------------- GEMM 128^2 / BK=64 / 4 waves: counted-vmcnt pipeline ------
// Used ONLY for N=1024 GEMMs (Wo, W2).
// EPI 2: +bias +resid fp32 | 3: +resid fp32
template <int EPI>
__global__ __launch_bounds__(256, 2)
void gemm128p(const uint16_t* __restrict__ A, const uint16_t* __restrict__ B,
              float* __restrict__ Cf, const float* __restrict__ bias,
              const float* __restrict__ resid, int M, int N, int K) {
    __shared__ uint8_t smem[65536];
    int bid = blockIdx.x;
    int cpx = gridDim.x >> 3;                      // grid divisible by 8
    bid = (bid & 7) * cpx + (bid >> 3);            // XCD-aware swizzle
    int nbn  = N >> 7;
    int brow = (bid / nbn) << 7;
    int bcol = (bid % nbn) << 7;
    int t0 = threadIdx.x;
    int wid = t0 >> 6, lane = t0 & 63;
    int wr = wid >> 1, wc = wid & 1;               // 2 x 2 wave grid
    int q = lane & 15, g = lane >> 4;

    const uint16_t* Asw = A + (size_t)(brow + (lane >> 3)) * K + (((lane & 7) ^ (lane >> 3)) << 3);
    const uint16_t* Bsw = B + (size_t)(bcol + (lane >> 3)) * K + (((lane & 7) ^ (lane >> 3)) << 3);

    f32x4 acc[4][4] = {};                          // [m2][n2]
    int NKT = K >> 6;

#define STG128(BSEL, KK)                                                       \
    {                                                                          \
        uint8_t* dA = smem + (BSEL) * 16384;                                   \
        uint8_t* dB = smem + 32768 + (BSEL) * 16384;                           \
        _Pragma("unroll")                                                      \
        for (int i = 0; i < 4; ++i) {                                          \
            int c = wid * 4 + i;                                               \
            gld_lds16(Asw + (size_t)(c * 8) * K + (KK), dA + c * 1024);        \
            gld_lds16(Bsw + (size_t)(c * 8) * K + (KK), dB + c * 1024);        \
        }                                                                      \
    }

    STG128(0, 0)

    for (int t = 0; t < NKT; ++t) {
        int cur = t & 1;
        if (t + 1 < NKT) {
            STG128(cur ^ 1, (t + 1) << 6)
            asm volatile("s_waitcnt vmcnt(8)" ::: "memory");
        } else {
            asm volatile("s_waitcnt vmcnt(0)" ::: "memory");
        }
        __builtin_amdgcn_sched_barrier(0);
        __builtin_amdgcn_s_barrier();
        __builtin_amdgcn_sched_barrier(0);

        const uint8_t* bA = smem + cur * 16384;
        const uint8_t* bB = smem + 32768 + cur * 16384;

        bf16x8 af[4][2], bfr[4][2];
        #pragma unroll
        for (int m2 = 0; m2 < 4; ++m2)
            #pragma unroll
            for (int ks = 0; ks < 2; ++ks) {
                int rr = wr * 64 + m2 * 16 + q;
                int sl = (ks * 4 + g) ^ (q & 7);
                af[m2][ks] = *(const bf16x8*)(bA + rr * 128 + sl * 16);
            }
        #pragma unroll
        for (int n2 = 0; n2 < 4; ++n2)
            #pragma unroll
            for (int ks = 0; ks < 2; ++ks) {
                int cc = wc * 64 + n2 * 16 + q;
                int sl = (ks * 4 + g) ^ (q & 7);
                bfr[n2][ks] = *(const bf16x8*)(bB + cc * 128 + sl * 16);
            }
        __builtin_amdgcn_s_setprio(1);
        #pragma unroll
        for (int m2 = 0; m2 < 4; ++m2)
            #pragma unroll
            for (int n2 = 0; n2 < 4; ++n2)
                #pragma unroll
                for (int ks = 0; ks < 2; ++ks)
                    acc[m2][n2] = __builtin_amdgcn_mfma_f32_16x16x32_bf16(
                        af[m2][ks], bfr[n2][ks], acc[m2][n2], 0, 0, 0);
        __builtin_amdgcn_s_setprio(0);
        __builtin_amdgcn_s_barrier();
    }

    #pragma unroll
    for (int m2 = 0; m2 < 4; ++m2)
        #pragma unroll
        for (int n2 = 0; n2 < 4; ++n2)
            #pragma unroll
            for (int r = 0; r < 4; ++r) {
                int gr = brow + wr * 64 + m2 * 16 + g * 4 + r;
                int gc = bcol + wc * 64 + n2 * 16 + q;
                float v = acc[m2][n2][r];
                size_t idx = (size_t)gr * N + gc;
                if constexpr (EPI == 2) {
                    Cf[idx] = v + bias[gc] + resid[idx];
                } else {
                    Cf[idx] = v + resid[idx];
                }
            }
#undef STG128
}

// ---------------- GEMM 256x128 / BK=32 / 4 waves / 2 blocks per CU ----------
// A [M][K], B [N][K] bf16 K-contiguous. C[M,N] bf16. Requires K%32==0.
// LDS 48 KiB: A dbuf 2x16K @0, B dbuf 2x8K @32K. Rows 64B (32 bf16);
// 16B-slot s of row r holds global k-group s^((r>>1)&3) (involution;
// pre-swizzled global src, linear gload_lds dest, same XOR on read ->
// 2-way bank pattern = free). Schedule = gemm128p's (counted vmcnt(6)).
// EPI 0: store bf16 | 1: +bias, relu, bf16
template <int EPI>
__global__ __launch_bounds__(256, 2)
void gemmBig(const uint16_t* __restrict__ A, const uint16_t* __restrict__ B,
             void* __restrict__ Cp, const float* __restrict__ bias,
             int M, int N, int K) {
    __shared__ uint8_t smem[49152];
    int bid = blockIdx.x;
    int cpx = gridDim.x >> 3;                      // grid divisible by 8
    bid = (bid & 7) * cpx + (bid >> 3);            // XCD-aware swizzle
    int nbn  = N >> 7;                             // 128-wide col tiles
    int brow = (bid / nbn) << 8;                   // 256-tall row tiles
    int bcol = (bid % nbn) << 7;
    int t0 = threadIdx.x;
    int wid = t0 >> 6, lane = t0 & 63;
    int wr = wid >> 1, wc = wid & 1;               // 2 x 2 wave grid
    int q = lane & 15, g = lane >> 4;

    // staging source: lane l -> row l>>2, k-group (l&3)^((l>>3)&3)
    int kswz = ((lane & 3) ^ ((lane >> 3) & 3)) << 3;
    const uint16_t* Asw = A + (size_t)(brow + (lane >> 2)) * K + kswz;
    const uint16_t* Bsw = B + (size_t)(bcol + (lane >> 2)) * K + kswz;

    f32x4 acc[8][4] = {};                          // [row-frag][col-frag]
    int NKT = K >> 5;

#define STGBIG(BSEL, KK)                                                       \
    {                                                                          \
        uint8_t* dA = smem + (BSEL) * 16384;                                   \
        uint8_t* dB = smem + 32768 + (BSEL) * 8192;                            \
        _Pragma("unroll")                                                      \
        for (int i = 0; i < 4; ++i) {                                          \
            int c = wid * 4 + i;                                               \
            gld_lds16(Asw + (size_t)(c * 16) * K + (KK), dA + c * 1024);       \
        }                                                                      \
        _Pragma("unroll")                                                      \
        for (int i = 0; i < 2; ++i) {                                          \
            int c = wid * 2 + i;                                               \
            gld_lds16(Bsw + (size_t)(c * 16) * K + (KK), dB + c * 1024);       \
        }                                                                      \
    }

    STGBIG(0, 0)

    for (int t = 0; t < NKT; ++t) {
        int cur = t & 1;
        if (t + 1 < NKT) {
            STGBIG(cur ^ 1, (t + 1) << 5)
            asm volatile("s_waitcnt vmcnt(6)" ::: "memory");
        } else {
            asm volatile("s_waitcnt vmcnt(0)" ::: "memory");
        }
        __builtin_amdgcn_sched_barrier(0);
        __builtin_amdgcn_s_barrier();
        __builtin_amdgcn_sched_barrier(0);

        const uint8_t* bA = smem + cur * 16384;
        const uint8_t* bB = smem + 32768 + cur * 8192;
        int sl = (g ^ ((q >> 1) & 3)) << 4;        // slot byte offset

        bf16x8 af[8], bfr[4];
        #pragma unroll
        for (int m8 = 0; m8 < 8; ++m8) {
            int rr = wr * 128 + m8 * 16 + q;
            af[m8] = *(const bf16x8*)(bA + rr * 64 + sl);
        }
        #pragma unroll
        for (int n4 = 0; n4 < 4; ++n4) {
            int cc = wc * 64 + n4 * 16 + q;
            bfr[n4] = *(const bf16x8*)(bB + cc * 64 + sl);
        }
        __builtin_amdgcn_s_setprio(1);
        #pragma unroll
        for (int m8 = 0; m8 < 8; ++m8)
            #pragma unroll
            for (int n4 = 0; n4 < 4; ++n4)
                acc[m8][n4] = __builtin_amdgcn_mfma_f32_16x16x32_bf16(
                    af[m8], bfr[n4], acc[m8][n4], 0, 0, 0);
        __builtin_amdgcn_s_setprio(0);
        __builtin_amdgcn_s_barrier();
    }

    uint16_t* Cb = (uint16_t*)Cp;
    #pragma unroll
    for (int m8 = 0; m8 < 8; ++m8)
        #pragma unroll
        for (int n4 = 0; n4 < 4; ++n4)
            #pragma unroll
            for (int r = 0; r < 4; ++r) {
                int gr = brow + wr * 128 + m8 * 16 + g * 4 + r;
                int gc = bcol + wc * 64 + n4 * 16 + q;
                float v = acc[m8][n4][r];
                if constexpr (EPI == 1) {
                    v += bias[gc];
                    v = v > 0.f ? v : 0.f;
                }
                Cb[(size_t)gr * N + gc] = f2bf(v);
            }
#undef STGBIG
}

// ---------------- flash attention v6: r10 version (proven ~192 us) ----------
// Q,K: [tok][8192] bf16 (Q cols 0..4095, K cols 4096..8191, head h at +h*256);
// Vt: [hd][4096 tok] bf16. Out ctx: [tok][4096] bf16.
__device__ __forceinline__ void attn_stage(uint8_t* smem, int bufsel,
        const uint16_t* Kb0, const uint16_t* Vb0, int ktok, int wid, int lane) {
    #pragma unroll
    for (int i = 0; i < 4; ++i) {
        int chunk = wid * 4 + i;                   // 0..15 (wave-uniform)
        int r = 2 * chunk + (lane >> 5);           // 0..31
        int s = lane & 31;
        int cg = (s & ~7) | ((s ^ r) & 7);
        gld_lds16(Kb0 + (size_t)(ktok + r) * 8192 + cg * 8,
                  smem + bufsel * 16384 + chunk * 1024);
    }
    #pragma unroll
    for (int i = 0; i < 4; ++i) {
        int chunk = wid * 4 + i;
        int r = 16 * chunk + (lane >> 2);          // 0..255
        int s = lane & 3;
        int cg = s ^ (r & 3);
        gld_lds16(Vb0 + (size_t)r * 4096 + ktok + cg * 8,
                  smem + 32768 + bufsel * 16384 + chunk * 1024);
    }
}

// online softmax (defer-max THR=8, per-lane partial l) + in-register P^T frag
__device__ __forceinline__ bf16x8 sm_pack(const f32x4* sacc, f32x4* acc,
                                          float& m_run, float& l_run,
                                          int q, int g) {
    float mx = fmaxf(fmaxf(fmaxf(sacc[0][0], sacc[0][1]), fmaxf(sacc[0][2], sacc[0][3])),
                     fmaxf(fmaxf(sacc[1][0], sacc[1][1]), fmaxf(sacc[1][2], sacc[1][3])));
    mx = fmaxf(mx, __shfl_xor(mx, 16));
    mx = fmaxf(mx, __shfl_xor(mx, 32));
    if (!__all(mx - m_run <= 8.f)) {
        float m_new = fmaxf(m_run, mx);
        float alpha = __expf(m_run - m_new);
        l_run *= alpha;
        #pragma unroll
        for (int td = 0; td < 16; ++td) {
            acc[td][0] *= alpha; acc[td][1] *= alpha;
            acc[td][2] *= alpha; acc[td][3] *= alpha;
        }
        m_run = m_new;
    }
    float p[8]; float rs = 0.f;
    #pragma unroll
    for (int tm = 0; tm < 2; ++tm)
        #pragma unroll
        for (int r = 0; r < 4; ++r) {
            float e = __expf(sacc[tm][r] - m_run);
            p[tm * 4 + r] = e; rs += e;
        }
    l_run += rs;                                   // per-lane partial; reduced at end

    uint32_t pk0 = pack2bf(p[0], p[1]);
    uint32_t pk1 = pack2bf(p[2], p[3]);
    uint32_t pk2 = pack2bf(p[4], p[5]);
    uint32_t pk3 = pack2bf(p[6], p[7]);
    int srcA = ((g & 1) << 5) + q;
    int srcB = srcA + 16;
    uint32_t a0 = __shfl(pk0, srcA), a1 = __shfl(pk2, srcA);
    uint32_t b0 = __shfl(pk1, srcA), b1 = __shfl(pk3, srcA);
    uint32_t c0 = __shfl(pk0, srcB), c1 = __shfl(pk2, srcB);
    uint32_t d0 = __shfl(pk1, srcB), d1 = __shfl(pk3, srcB);
    bool hi = g >= 2;
    uint4 pb;
    pb.x = hi ? a1 : a0;
    pb.y = hi ? b1 : b0;
    pb.z = hi ? c1 : c0;
    pb.w = hi ? d1 : d0;
    return __builtin_bit_cast(bf16x8, pb);
}

__global__ __launch_bounds__(256, 2)
void attn(const uint16_t* __restrict__ Qg, const uint16_t* __restrict__ Kg,
          const uint16_t* __restrict__ Vtg, uint16_t* __restrict__ Og) {
    const int S = 2048, NT = 64, QKS = 8192, OC = 4096;
    __shared__ uint8_t smem[65536];

    int id = blockIdx.x;
    id = (id & 7) * 64 + (id >> 3);                // XCD swizzle (512 blocks)
    int qb = id & 15, h = (id >> 4) & 15, b = id >> 8;

    int t = threadIdx.x;
    int wid = t >> 6, lane = t & 63;
    int q = lane & 15, g = lane >> 4;
    int tok0 = b * S + qb * 128 + wid * 32;        // 32 q-rows per wave

    bf16x8 qf0[8], qf1[8];
    {
        const uint16_t* qrow0 = Qg + (size_t)(tok0 + q) * QKS + h * 256 + g * 8;
        const uint16_t* qrow1 = Qg + (size_t)(tok0 + 16 + q) * QKS + h * 256 + g * 8;
        #pragma unroll
        for (int c = 0; c < 8; ++c) {
            bf16x8 r0 = *(const bf16x8*)(qrow0 + c * 32);
            bf16x8 r1 = *(const bf16x8*)(qrow1 + c * 32);
            #pragma unroll
            for (int i = 0; i < 8; ++i) {
                r0[i] = (__bf16)((float)r0[i] * 0.0625f);
                r1[i] = (__bf16)((float)r1[i] * 0.0625f);
            }
            qf0[c] = r0; qf1[c] = r1;
        }
    }

    f32x4 acc0[16] = {}, acc1[16] = {};
    float m0 = -1e30f, l0 = 0.f;
    float m1 = -1e30f, l1 = 0.f;

    const uint16_t* Kb0 = Kg + (size_t)(b * S) * QKS + h * 256;
    const uint16_t* Vb0 = Vtg + (size_t)(h * 256) * 4096 + b * S;

    attn_stage(smem, 0, Kb0, Vb0, 0, wid, lane);

    for (int kt = 0; kt < NT; ++kt) {
        int cb = (kt & 1) * 16384;
        if (kt + 1 < NT) {
            attn_stage(smem, (kt + 1) & 1, Kb0, Vb0, (kt + 1) * 32, wid, lane);
            asm volatile("s_waitcnt vmcnt(8)" ::: "memory");
        } else {
            asm volatile("s_waitcnt vmcnt(0)" ::: "memory");
        }
        __builtin_amdgcn_sched_barrier(0);
        __builtin_amdgcn_s_barrier();

        const uint16_t* sk = (const uint16_t*)(smem + cb);
        const uint16_t* sv = (const uint16_t*)(smem + 32768 + cb);

        f32x4 sA0[2] = {}, sA1[2] = {};
        __builtin_amdgcn_s_setprio(1);
        #pragma unroll
        for (int c = 0; c < 8; ++c) {
            #pragma unroll
            for (int tm = 0; tm < 2; ++tm) {
                int G = c * 4 + g;
                int slot = (G & ~7) | ((G ^ q) & 7);
                bf16x8 kf = *(const bf16x8*)(sk + (tm * 16 + q) * 256 + slot * 8);
                sA0[tm] = __builtin_amdgcn_mfma_f32_16x16x32_bf16(kf, qf0[c], sA0[tm], 0, 0, 0);
                sA1[tm] = __builtin_amdgcn_mfma_f32_16x16x32_bf16(kf, qf1[c], sA1[tm], 0, 0, 0);
            }
        }
        __builtin_amdgcn_s_setprio(0);

        bf16x8 pfrag0 = sm_pack(sA0, acc0, m0, l0, q, g);
        bf16x8 pfrag1 = sm_pack(sA1, acc1, m1, l1, q, g);

        int sl = g ^ (q & 3);
        __builtin_amdgcn_s_setprio(1);
        #pragma unroll
        for (int td = 0; td < 16; ++td) {
            bf16x8 vf = *(const bf16x8*)(sv + (td * 16 + q) * 32 + sl * 8);
            acc0[td] = __builtin_amdgcn_mfma_f32_16x16x32_bf16(vf, pfrag0, acc0[td], 0, 0, 0);
            acc1[td] = __builtin_amdgcn_mfma_f32_16x16x32_bf16(vf, pfrag1, acc1[td], 0, 0, 0);
        }
        __builtin_amdgcn_s_setprio(0);
        __builtin_amdgcn_s_barrier();
    }

    // deferred l reduction (sum over the 4 g-lanes of each q)
    l0 += __shfl_xor(l0, 16); l0 += __shfl_xor(l0, 32);
    l1 += __shfl_xor(l1, 16); l1 += __shfl_xor(l1, 32);

    __syncthreads();
    {
        float inv0 = 1.f / l0, inv1 = 1.f / l1;
        uint32_t* w0 = (uint32_t*)(smem + wid * 16384);
        uint32_t* w1 = (uint32_t*)(smem + wid * 16384 + 8192);
        #pragma unroll
        for (int td = 0; td < 16; ++td) {
            int base = (q * 256 + td * 16 + g * 4) >> 1;
            w0[base]     = pack2bf(acc0[td][0] * inv0, acc0[td][1] * inv0);
            w0[base + 1] = pack2bf(acc0[td][2] * inv0, acc0[td][3] * inv0);
            w1[base]     = pack2bf(acc1[td][0] * inv1, acc1[td][1] * inv1);
            w1[base + 1] = pack2bf(acc1[td][2] * inv1, acc1[td][3] * inv1);
        }
    }
    __syncthreads();
    #pragma unroll
    for (int s2 = 0; s2 < 2; ++s2) {
        const uint16_t* tb = (const uint16_t*)(smem + wid * 16384 + s2 * 8192);
        #pragma unroll
        for (int r2 = 0; r2 < 8; ++r2) {
            int c = r2 * 64 + lane;
            int qq = c >> 5, dc = c & 31;
            uint4 v = *(const uint4*)&tb[qq * 256 + dc * 8];
            *(uint4*)(Og + (size_t)(tok0 + s2 * 16 + qq) * OC + h * 256 + dc * 8) = v;
        }
    }
}

// ---------------------------------------------------------------------------
extern "C" void kernel_launch(void* const* d_in, const int* in_sizes, int n_in,
                              void* d_out, int out_size, void* d_ws, size_t ws_size,
                              hipStream_t stream) {
    const float* x   = (const float*)d_in[0];
    const float* Wq  = (const float*)d_in[1];
    const float* Wk  = (const float*)d_in[2];
    const float* Wv  = (const float*)d_in[3];
    const float* Wo  = (const float*)d_in[4];
    const float* W1  = (const float*)d_in[5];
    const float* b1  = (const float*)d_in[6];
    const float* W2  = (const float*)d_in[7];
    const float* b2  = (const float*)d_in[8];
    const float* g1  = (const float*)d_in[9];
    const float* be1 = (const float*)d_in[10];
    const float* g2  = (const float*)d_in[11];
    const float* be2 = (const float*)d_in[12];

    char* ws = (char*)d_ws;
    const size_t M8 = 8388608;  // 8 MiB
    uint16_t* WqkT = (uint16_t*)(ws + 0 * M8);   // [8192][1024]: WqT then WkT
    uint16_t* WqT  = WqkT;                        // [4096][1024]
    uint16_t* WkT  = (uint16_t*)(ws + 1 * M8);
    uint16_t* WvT  = (uint16_t*)(ws + 2 * M8);
    uint16_t* WoT  = (uint16_t*)(ws + 3 * M8);   // [1024][4096]
    uint16_t* W1T  = (uint16_t*)(ws + 4 * M8);
    uint16_t* W2T  = (uint16_t*)(ws + 5 * M8);   // [1024][4096]
    uint16_t* x1   = (uint16_t*)(ws + 6 * M8);   // [4096][1024]
    uint16_t* x2   = (uint16_t*)(ws + 7 * M8);
    uint16_t* QK   = (uint16_t*)(ws + 8 * M8);   // [4096][8192] (Q | K)
    uint16_t* Vt   = (uint16_t*)(ws + 16 * M8);  // [hd][tok]
    uint16_t* ctx  = (uint16_t*)(ws + 20 * M8);
    float*    xmid = (float*)(ws + 12 * M8);     // reuse QK upper (dead after attn)
    uint16_t* Hn   = (uint16_t*)(ws + 8 * M8);   // reuse QK lower (dead after attn)

    // weight convert+transpose (batched; WqT/WkT adjacent -> [8192][1024])
    wconvB<<<dim3(128, 32, 3), 256, 0, stream>>>(Wq, Wk, Wv, WqT, WkT, WvT, 1024, 4096);
    wconvB<<<dim3(32, 128, 2), 256, 0, stream>>>(Wo, W2, nullptr, WoT, W2T, nullptr, 4096, 1024);
    wconvB<<<dim3(128, 32, 1), 256, 0, stream>>>(W1, nullptr, nullptr, W1T, nullptr, nullptr, 1024, 4096);

    // pre-norm 1
    ln_bf16<<<4096, 256, 0, stream>>>(x, g1, be1, x1);

    // merged Q|K projection + V^T projection (256x128 BK=32, 2 blocks/CU)
    gemmBig<0><<<1024, 256, 0, stream>>>(x1, WqkT, QK, nullptr, 4096, 8192, 1024);
    gemmBig<0><<<512, 256, 0, stream>>>(WvT, x1, Vt, nullptr, 4096, 4096, 1024);

    // attention (512 blocks x 256 threads, 32 q-rows/wave)
    attn<<<512, 256, 0, stream>>>(QK, QK + 4096, Vt, ctx);

    // Wo projection + residual -> xmid (fp32), 128^2 BK=64 pipeline
    gemm128p<3><<<256, 256, 0, stream>>>(ctx, WoT, xmid, nullptr, x, 4096, 1024, 4096);

    // pre-norm 2
    ln_bf16<<<4096, 256, 0, stream>>>(xmid, g2, be2, x2);

    // FFN
    gemmBig<1><<<512, 256, 0, stream>>>(x2, W1T, Hn, b1, 4096, 4096, 1024);
    gemm128p<2><<<256, 256, 0, stream>>>(Hn, W2T, (float*)d_out, b2, xmid, 4096, 1024, 4096);
}

// Round 15
// 449.670 us; speedup vs baseline: 1.0487x; 1.0487x over previous
//
#include <hip/hip_runtime.h>
#include <hip/hip_bf16.h>
#include <stdint.h>

using bf16x8 = __attribute__((ext_vector_type(8))) __bf16;
using f32x4  = __attribute__((ext_vector_type(4))) float;

__device__ __forceinline__ uint16_t f2bf(float f) {
    uint32_t u = __builtin_bit_cast(uint32_t, f);
    u += 0x7FFFu + ((u >> 16) & 1u);
    return (uint16_t)(u >> 16);
}
__device__ __forceinline__ uint32_t pack2bf(float lo, float hi) {
    return (uint32_t)f2bf(lo) | ((uint32_t)f2bf(hi) << 16);
}

__device__ __forceinline__ void gld_lds16(const void* g, void* l) {
    __builtin_amdgcn_global_load_lds(
        (const __attribute__((address_space(1))) void*)g,
        (__attribute__((address_space(3))) void*)l,
        16, 0, 0);
}

// ------- unified weight convert+transpose: 6 weights, one launch ------------
// z<4: [1024][4096] -> [4096][1024] (Wq,Wk,Wv,W1); z>=4: [4096][1024] ->
// [1024][4096] (Wo,W2). Grid 128x32x6; z>=4 swaps block-coordinate roles.
__global__ __launch_bounds__(256)
void wconv6(const float* __restrict__ iq, const float* __restrict__ ik,
            const float* __restrict__ iv, const float* __restrict__ i1,
            const float* __restrict__ io, const float* __restrict__ i2,
            uint16_t* __restrict__ oq, uint16_t* __restrict__ ok,
            uint16_t* __restrict__ ov, uint16_t* __restrict__ o1,
            uint16_t* __restrict__ oo, uint16_t* __restrict__ o2) {
    int z = blockIdx.z;
    const float* in;
    uint16_t* out;
    int R, C, c0, r0;
    if (z < 4) {
        in  = z == 0 ? iq : z == 1 ? ik : z == 2 ? iv : i1;
        out = z == 0 ? oq : z == 1 ? ok : z == 2 ? ov : o1;
        R = 1024; C = 4096;
        c0 = blockIdx.x * 32; r0 = blockIdx.y * 32;
    } else {
        in  = z == 4 ? io : i2;
        out = z == 4 ? oo : o2;
        R = 4096; C = 1024;
        c0 = blockIdx.y * 32; r0 = blockIdx.x * 32;
    }
    __shared__ float t[32][33];
    int tx = threadIdx.x & 31, ty = threadIdx.x >> 5;  // 32 x 8
    #pragma unroll
    for (int i = 0; i < 32; i += 8)
        t[ty + i][tx] = in[(size_t)(r0 + ty + i) * C + c0 + tx];
    __syncthreads();
    #pragma unroll
    for (int i = 0; i < 32; i += 8)
        out[(size_t)(c0 + ty + i) * R + r0 + tx] = f2bf(t[tx][ty + i]);
}

// ---------------- LayerNorm fp32 -> bf16, D = 1024, one row per block -------
__global__ __launch_bounds__(256)
void ln_bf16(const float* __restrict__ x, const float* __restrict__ gw,
             const float* __restrict__ bw, uint16_t* __restrict__ out) {
    const int D = 1024;
    int row = blockIdx.x;
    float4 v = ((const float4*)(x + (size_t)row * D))[threadIdx.x];
    float s  = v.x + v.y + v.z + v.w;
    float ss = v.x * v.x + v.y * v.y + v.z * v.z + v.w * v.w;
    #pragma unroll
    for (int m = 1; m < 64; m <<= 1) {
        s  += __shfl_xor(s, m);
        ss += __shfl_xor(ss, m);
    }
    __shared__ float red[8];
    int wid = threadIdx.x >> 6, lane = threadIdx.x & 63;
    if (lane == 0) { red[wid] = s; red[4 + wid] = ss; }
    __syncthreads();
    s  = red[0] + red[1] + red[2] + red[3];
    ss = red[4] + red[5] + red[6] + red[7];
    float mu  = s * (1.f / 1024.f);
    float var = ss * (1.f / 1024.f) - mu * mu;
    float rstd = rsqrtf(var + 1e-5f);
    float4 gv = ((const float4*)gw)[threadIdx.x];
    float4 bv = ((const float4*)bw)[threadIdx.x];
    ushort4 o;
    o.x = f2bf((v.x - mu) * rstd * gv.x + bv.x);
    o.y = f2bf((v.y - mu) * rstd * gv.y + bv.y);
    o.z = f2bf((v.z - mu) * rstd * gv.z + bv.z);
    o.w = f2bf((v.w - mu) * rstd * gv.w + bv.w);
    ((ushort4*)(out + (size_t)row * D))[threadIdx.x] = o;
}

// ---------------- GEMM 128^2 / BK=64 / 4 waves: counted-vmcnt pipeline ------
// Used ONLY for N=1024 GEMMs (Wo, W2).
// EPI 2: +bias +resid fp32 | 3: +resid fp32
template <int EPI>
__global__ __launch_bounds__(256, 2)
void gemm128p(const uint16_t* __restrict__ A, const uint16_t* __restrict__ B,
              float* __restrict__ Cf, const float* __restrict__ bias,
              const float* __restrict__ resid, int M, int N, int K) {
    __shared__ uint8_t smem[65536];
    int bid = blockIdx.x;
    int cpx = gridDim.x >> 3;                      // grid divisible by 8
    bid = (bid & 7) * cpx + (bid >> 3);            // XCD-aware swizzle
    int nbn  = N >> 7;
    int brow = (bid / nbn) << 7;
    int bcol = (bid % nbn) << 7;
    int t0 = threadIdx.x;
    int wid = t0 >> 6, lane = t0 & 63;
    int wr = wid >> 1, wc = wid & 1;               // 2 x 2 wave grid
    int q = lane & 15, g = lane >> 4;

    const uint16_t* Asw = A + (size_t)(brow + (lane >> 3)) * K + (((lane & 7) ^ (lane >> 3)) << 3);
    const uint16_t* Bsw = B + (size_t)(bcol + (lane >> 3)) * K + (((lane & 7) ^ (lane >> 3)) << 3);

    f32x4 acc[4][4] = {};                          // [m2][n2]
    int NKT = K >> 6;

#define STG128(BSEL, KK)                                                       \
    {                                                                          \
        uint8_t* dA = smem + (BSEL) * 16384;                                   \
        uint8_t* dB = smem + 32768 + (BSEL) * 16384;                           \
        _Pragma("unroll")                                                      \
        for (int i = 0; i < 4; ++i) {                                          \
            int c = wid * 4 + i;                                               \
            gld_lds16(Asw + (size_t)(c * 8) * K + (KK), dA + c * 1024);        \
            gld_lds16(Bsw + (size_t)(c * 8) * K + (KK), dB + c * 1024);        \
        }                                                                      \
    }

    STG128(0, 0)

    for (int t = 0; t < NKT; ++t) {
        int cur = t & 1;
        if (t + 1 < NKT) {
            STG128(cur ^ 1, (t + 1) << 6)
            asm volatile("s_waitcnt vmcnt(8)" ::: "memory");
        } else {
            asm volatile("s_waitcnt vmcnt(0)" ::: "memory");
        }
        __builtin_amdgcn_sched_barrier(0);
        __builtin_amdgcn_s_barrier();
        __builtin_amdgcn_sched_barrier(0);

        const uint8_t* bA = smem + cur * 16384;
        const uint8_t* bB = smem + 32768 + cur * 16384;

        bf16x8 af[4][2], bfr[4][2];
        #pragma unroll
        for (int m2 = 0; m2 < 4; ++m2)
            #pragma unroll
            for (int ks = 0; ks < 2; ++ks) {
                int rr = wr * 64 + m2 * 16 + q;
                int sl = (ks * 4 + g) ^ (q & 7);
                af[m2][ks] = *(const bf16x8*)(bA + rr * 128 + sl * 16);
            }
        #pragma unroll
        for (int n2 = 0; n2 < 4; ++n2)
            #pragma unroll
            for (int ks = 0; ks < 2; ++ks) {
                int cc = wc * 64 + n2 * 16 + q;
                int sl = (ks * 4 + g) ^ (q & 7);
                bfr[n2][ks] = *(const bf16x8*)(bB + cc * 128 + sl * 16);
            }
        __builtin_amdgcn_s_setprio(1);
        #pragma unroll
        for (int m2 = 0; m2 < 4; ++m2)
            #pragma unroll
            for (int n2 = 0; n2 < 4; ++n2)
                #pragma unroll
                for (int ks = 0; ks < 2; ++ks)
                    acc[m2][n2] = __builtin_amdgcn_mfma_f32_16x16x32_bf16(
                        af[m2][ks], bfr[n2][ks], acc[m2][n2], 0, 0, 0);
        __builtin_amdgcn_s_setprio(0);
        __builtin_amdgcn_s_barrier();
    }

    #pragma unroll
    for (int m2 = 0; m2 < 4; ++m2)
        #pragma unroll
        for (int n2 = 0; n2 < 4; ++n2)
            #pragma unroll
            for (int r = 0; r < 4; ++r) {
                int gr = brow + wr * 64 + m2 * 16 + g * 4 + r;
                int gc = bcol + wc * 64 + n2 * 16 + q;
                float v = acc[m2][n2][r];
                size_t idx = (size_t)gr * N + gc;
                if constexpr (EPI == 2) {
                    Cf[idx] = v + bias[gc] + resid[idx];
                } else {
                    Cf[idx] = v + resid[idx];
                }
            }
#undef STG128
}

// ---------------- GEMM 256^2 / BK=64 / 8 waves: counted-vmcnt pipeline ------
// (r7-proven version; used for all M,N >= 4096 GEMMs)
// EPI 0: store bf16 | 1: +bias, relu, bf16
template <int EPI>
__global__ __launch_bounds__(512, 2)
void gemm256(const uint16_t* __restrict__ A, const uint16_t* __restrict__ B,
             void* __restrict__ Cp, const float* __restrict__ bias,
             int M, int N, int K) {
    __shared__ uint8_t smem[131072];
    int bid = blockIdx.x;
    int cpx = gridDim.x >> 3;                      // grid divisible by 8
    bid = (bid & 7) * cpx + (bid >> 3);            // XCD-aware swizzle
    int nbn  = N >> 8;
    int brow = (bid / nbn) << 8;
    int bcol = (bid % nbn) << 8;
    int t0 = threadIdx.x;
    int wid = t0 >> 6, lane = t0 & 63;
    int wr = wid >> 2, wc = wid & 3;               // 2 x 4 wave grid
    int q = lane & 15, g = lane >> 4;

    const uint16_t* Asw = A + (size_t)(brow + (lane >> 3)) * K + (((lane & 7) ^ (lane >> 3)) << 3);
    const uint16_t* Bsw = B + (size_t)(bcol + (lane >> 3)) * K + (((lane & 7) ^ (lane >> 3)) << 3);

    f32x4 acc[2][2][4][2] = {};                    // [mh][nh][m2][n2]
    int NKT = K >> 6;

#define STAGE256(BSEL, KK)                                                     \
    {                                                                          \
        uint8_t* dA = smem + (BSEL) * 32768;                                   \
        uint8_t* dB = smem + 65536 + (BSEL) * 32768;                           \
        _Pragma("unroll")                                                      \
        for (int i = 0; i < 4; ++i) {                                          \
            int c = wid * 4 + i;                                               \
            gld_lds16(Asw + (size_t)(c * 8) * K + (KK), dA + c * 1024);        \
            gld_lds16(Bsw + (size_t)(c * 8) * K + (KK), dB + c * 1024);        \
        }                                                                      \
    }

    STAGE256(0, 0)                                  // prologue: tile 0

    for (int t = 0; t < NKT; ++t) {
        int cur = t & 1;
        if (t + 1 < NKT) {
            STAGE256(cur ^ 1, (t + 1) << 6)        // next tile in flight
            asm volatile("s_waitcnt vmcnt(8)" ::: "memory");  // tile t landed
        } else {
            asm volatile("s_waitcnt vmcnt(0)" ::: "memory");
        }
        __builtin_amdgcn_sched_barrier(0);
        __builtin_amdgcn_s_barrier();
        __builtin_amdgcn_sched_barrier(0);

        const uint8_t* bA = smem + cur * 32768;
        const uint8_t* bB = smem + 65536 + cur * 32768;

        bf16x8 af[4][2], bfr[2][2];

#define LOADA256(MH)                                                           \
        _Pragma("unroll")                                                      \
        for (int m2 = 0; m2 < 4; ++m2)                                         \
            _Pragma("unroll")                                                  \
            for (int ks = 0; ks < 2; ++ks) {                                   \
                int rr = wr * 128 + (MH) * 64 + m2 * 16 + q;                   \
                int sl = (ks * 4 + g) ^ (q & 7);                               \
                af[m2][ks] = *(const bf16x8*)(bA + rr * 128 + sl * 16);        \
            }
#define LOADB256(NH)                                                           \
        _Pragma("unroll")                                                      \
        for (int n2 = 0; n2 < 2; ++n2)                                         \
            _Pragma("unroll")                                                  \
            for (int ks = 0; ks < 2; ++ks) {                                   \
                int cc = wc * 64 + (NH) * 32 + n2 * 16 + q;                    \
                int sl = (ks * 4 + g) ^ (q & 7);                               \
                bfr[n2][ks] = *(const bf16x8*)(bB + cc * 128 + sl * 16);       \
            }
#define MMQ256(MH, NH)                                                         \
        __builtin_amdgcn_s_setprio(1);                                         \
        _Pragma("unroll")                                                      \
        for (int m2 = 0; m2 < 4; ++m2)                                         \
            _Pragma("unroll")                                                  \
            for (int n2 = 0; n2 < 2; ++n2)                                     \
                _Pragma("unroll")                                              \
                for (int ks = 0; ks < 2; ++ks)                                 \
                    acc[MH][NH][m2][n2] = __builtin_amdgcn_mfma_f32_16x16x32_bf16( \
                        af[m2][ks], bfr[n2][ks], acc[MH][NH][m2][n2], 0, 0, 0);\
        __builtin_amdgcn_s_setprio(0);

        LOADA256(0) LOADB256(0) MMQ256(0, 0)
        LOADB256(1) MMQ256(0, 1)
        LOADA256(1) MMQ256(1, 1)
        LOADB256(0) MMQ256(1, 0)

        __builtin_amdgcn_s_barrier();              // buf[cur] reusable
    }

    uint16_t* Cb = (uint16_t*)Cp;
    #pragma unroll
    for (int mh = 0; mh < 2; ++mh)
        #pragma unroll
        for (int nh = 0; nh < 2; ++nh)
            #pragma unroll
            for (int m2 = 0; m2 < 4; ++m2)
                #pragma unroll
                for (int n2 = 0; n2 < 2; ++n2)
                    #pragma unroll
                    for (int r = 0; r < 4; ++r) {
                        int gr = brow + wr * 128 + mh * 64 + m2 * 16 + g * 4 + r;
                        int gc = bcol + wc * 64 + nh * 32 + n2 * 16 + q;
                        float v = acc[mh][nh][m2][n2][r];
                        if constexpr (EPI == 1) {
                            v += bias[gc];
                            v = v > 0.f ? v : 0.f;
                        }
                        Cb[(size_t)gr * N + gc] = f2bf(v);
                    }
#undef STAGE256
#undef LOADA256
#undef LOADB256
#undef MMQ256
}

// ---------------- flash attention v6: r10 version (proven ~192 us) ----------
// Q,K: [tok][8192] bf16 (Q cols 0..4095, K cols 4096..8191, head h at +h*256);
// Vt: [hd][4096 tok] bf16. Out ctx: [tok][4096] bf16.
__device__ __forceinline__ void attn_stage(uint8_t* smem, int bufsel,
        const uint16_t* Kb0, const uint16_t* Vb0, int ktok, int wid, int lane) {
    #pragma unroll
    for (int i = 0; i < 4; ++i) {
        int chunk = wid * 4 + i;                   // 0..15 (wave-uniform)
        int r = 2 * chunk + (lane >> 5);           // 0..31
        int s = lane & 31;
        int cg = (s & ~7) | ((s ^ r) & 7);
        gld_lds16(Kb0 + (size_t)(ktok + r) * 8192 + cg * 8,
                  smem + bufsel * 16384 + chunk * 1024);
    }
    #pragma unroll
    for (int i = 0; i < 4; ++i) {
        int chunk = wid * 4 + i;
        int r = 16 * chunk + (lane >> 2);          // 0..255
        int s = lane & 3;
        int cg = s ^ (r & 3);
        gld_lds16(Vb0 + (size_t)r * 4096 + ktok + cg * 8,
                  smem + 32768 + bufsel * 16384 + chunk * 1024);
    }
}

// online softmax (defer-max THR=8, per-lane partial l) + in-register P^T frag
__device__ __forceinline__ bf16x8 sm_pack(const f32x4* sacc, f32x4* acc,
                                          float& m_run, float& l_run,
                                          int q, int g) {
    float mx = fmaxf(fmaxf(fmaxf(sacc[0][0], sacc[0][1]), fmaxf(sacc[0][2], sacc[0][3])),
                     fmaxf(fmaxf(sacc[1][0], sacc[1][1]), fmaxf(sacc[1][2], sacc[1][3])));
    mx = fmaxf(mx, __shfl_xor(mx, 16));
    mx = fmaxf(mx, __shfl_xor(mx, 32));
    if (!__all(mx - m_run <= 8.f)) {
        float m_new = fmaxf(m_run, mx);
        float alpha = __expf(m_run - m_new);
        l_run *= alpha;
        #pragma unroll
        for (int td = 0; td < 16; ++td) {
            acc[td][0] *= alpha; acc[td][1] *= alpha;
            acc[td][2] *= alpha; acc[td][3] *= alpha;
        }
        m_run = m_new;
    }
    float p[8]; float rs = 0.f;
    #pragma unroll
    for (int tm = 0; tm < 2; ++tm)
        #pragma unroll
        for (int r = 0; r < 4; ++r) {
            float e = __expf(sacc[tm][r] - m_run);
            p[tm * 4 + r] = e; rs += e;
        }
    l_run += rs;                                   // per-lane partial; reduced at end

    uint32_t pk0 = pack2bf(p[0], p[1]);
    uint32_t pk1 = pack2bf(p[2], p[3]);
    uint32_t pk2 = pack2bf(p[4], p[5]);
    uint32_t pk3 = pack2bf(p[6], p[7]);
    int srcA = ((g & 1) << 5) + q;
    int srcB = srcA + 16;
    uint32_t a0 = __shfl(pk0, srcA), a1 = __shfl(pk2, srcA);
    uint32_t b0 = __shfl(pk1, srcA), b1 = __shfl(pk3, srcA);
    uint32_t c0 = __shfl(pk0, srcB), c1 = __shfl(pk2, srcB);
    uint32_t d0 = __shfl(pk1, srcB), d1 = __shfl(pk3, srcB);
    bool hi = g >= 2;
    uint4 pb;
    pb.x = hi ? a1 : a0;
    pb.y = hi ? b1 : b0;
    pb.z = hi ? c1 : c0;
    pb.w = hi ? d1 : d0;
    return __builtin_bit_cast(bf16x8, pb);
}

__global__ __launch_bounds__(256, 2)
void attn(const uint16_t* __restrict__ Qg, const uint16_t* __restrict__ Kg,
          const uint16_t* __restrict__ Vtg, uint16_t* __restrict__ Og) {
    const int S = 2048, NT = 64, QKS = 8192, OC = 4096;
    __shared__ uint8_t smem[65536];

    int id = blockIdx.x;
    id = (id & 7) * 64 + (id >> 3);                // XCD swizzle (512 blocks)
    int qb = id & 15, h = (id >> 4) & 15, b = id >> 8;

    int t = threadIdx.x;
    int wid = t >> 6, lane = t & 63;
    int q = lane & 15, g = lane >> 4;
    int tok0 = b * S + qb * 128 + wid * 32;        // 32 q-rows per wave

    bf16x8 qf0[8], qf1[8];
    {
        const uint16_t* qrow0 = Qg + (size_t)(tok0 + q) * QKS + h * 256 + g * 8;
        const uint16_t* qrow1 = Qg + (size_t)(tok0 + 16 + q) * QKS + h * 256 + g * 8;
        #pragma unroll
        for (int c = 0; c < 8; ++c) {
            bf16x8 r0 = *(const bf16x8*)(qrow0 + c * 32);
            bf16x8 r1 = *(const bf16x8*)(qrow1 + c * 32);
            #pragma unroll
            for (int i = 0; i < 8; ++i) {
                r0[i] = (__bf16)((float)r0[i] * 0.0625f);
                r1[i] = (__bf16)((float)r1[i] * 0.0625f);
            }
            qf0[c] = r0; qf1[c] = r1;
        }
    }

    f32x4 acc0[16] = {}, acc1[16] = {};
    float m0 = -1e30f, l0 = 0.f;
    float m1 = -1e30f, l1 = 0.f;

    const uint16_t* Kb0 = Kg + (size_t)(b * S) * QKS + h * 256;
    const uint16_t* Vb0 = Vtg + (size_t)(h * 256) * 4096 + b * S;

    attn_stage(smem, 0, Kb0, Vb0, 0, wid, lane);

    for (int kt = 0; kt < NT; ++kt) {
        int cb = (kt & 1) * 16384;
        if (kt + 1 < NT) {
            attn_stage(smem, (kt + 1) & 1, Kb0, Vb0, (kt + 1) * 32, wid, lane);
            asm volatile("s_waitcnt vmcnt(8)" ::: "memory");
        } else {
            asm volatile("s_waitcnt vmcnt(0)" ::: "memory");
        }
        __builtin_amdgcn_sched_barrier(0);
        __builtin_amdgcn_s_barrier();

        const uint16_t* sk = (const uint16_t*)(smem + cb);
        const uint16_t* sv = (const uint16_t*)(smem + 32768 + cb);

        f32x4 sA0[2] = {}, sA1[2] = {};
        __builtin_amdgcn_s_setprio(1);
        #pragma unroll
        for (int c = 0; c < 8; ++c) {
            #pragma unroll
            for (int tm = 0; tm < 2; ++tm) {
                int G = c * 4 + g;
                int slot = (G & ~7) | ((G ^ q) & 7);
                bf16x8 kf = *(const bf16x8*)(sk + (tm * 16 + q) * 256 + slot * 8);
                sA0[tm] = __builtin_amdgcn_mfma_f32_16x16x32_bf16(kf, qf0[c], sA0[tm], 0, 0, 0);
                sA1[tm] = __builtin_amdgcn_mfma_f32_16x16x32_bf16(kf, qf1[c], sA1[tm], 0, 0, 0);
            }
        }
        __builtin_amdgcn_s_setprio(0);

        bf16x8 pfrag0 = sm_pack(sA0, acc0, m0, l0, q, g);
        bf16x8 pfrag1 = sm_pack(sA1, acc1, m1, l1, q, g);

        int sl = g ^ (q & 3);
        __builtin_amdgcn_s_setprio(1);
        #pragma unroll
        for (int td = 0; td < 16; ++td) {
            bf16x8 vf = *(const bf16x8*)(sv + (td * 16 + q) * 32 + sl * 8);
            acc0[td] = __builtin_amdgcn_mfma_f32_16x16x32_bf16(vf, pfrag0, acc0[td], 0, 0, 0);
            acc1[td] = __builtin_amdgcn_mfma_f32_16x16x32_bf16(vf, pfrag1, acc1[td], 0, 0, 0);
        }
        __builtin_amdgcn_s_setprio(0);
        __builtin_amdgcn_s_barrier();
    }

    // deferred l reduction (sum over the 4 g-lanes of each q)
    l0 += __shfl_xor(l0, 16); l0 += __shfl_xor(l0, 32);
    l1 += __shfl_xor(l1, 16); l1 += __shfl_xor(l1, 32);

    __syncthreads();
    {
        float inv0 = 1.f / l0, inv1 = 1.f / l1;
        uint32_t* w0 = (uint32_t*)(smem + wid * 16384);
        uint32_t* w1 = (uint32_t*)(smem + wid * 16384 + 8192);
        #pragma unroll
        for (int td = 0; td < 16; ++td) {
            int base = (q * 256 + td * 16 + g * 4) >> 1;
            w0[base]     = pack2bf(acc0[td][0] * inv0, acc0[td][1] * inv0);
            w0[base + 1] = pack2bf(acc0[td][2] * inv0, acc0[td][3] * inv0);
            w1[base]     = pack2bf(acc1[td][0] * inv1, acc1[td][1] * inv1);
            w1[base + 1] = pack2bf(acc1[td][2] * inv1, acc1[td][3] * inv1);
        }
    }
    __syncthreads();
    #pragma unroll
    for (int s2 = 0; s2 < 2; ++s2) {
        const uint16_t* tb = (const uint16_t*)(smem + wid * 16384 + s2 * 8192);
        #pragma unroll
        for (int r2 = 0; r2 < 8; ++r2) {
            int c = r2 * 64 + lane;
            int qq = c >> 5, dc = c & 31;
            uint4 v = *(const uint4*)&tb[qq * 256 + dc * 8];
            *(uint4*)(Og + (size_t)(tok0 + s2 * 16 + qq) * OC + h * 256 + dc * 8) = v;
        }
    }
}

// ---------------------------------------------------------------------------
extern "C" void kernel_launch(void* const* d_in, const int* in_sizes, int n_in,
                              void* d_out, int out_size, void* d_ws, size_t ws_size,
                              hipStream_t stream) {
    const float* x   = (const float*)d_in[0];
    const float* Wq  = (const float*)d_in[1];
    const float* Wk  = (const float*)d_in[2];
    const float* Wv  = (const float*)d_in[3];
    const float* Wo  = (const float*)d_in[4];
    const float* W1  = (const float*)d_in[5];
    const float* b1  = (const float*)d_in[6];
    const float* W2  = (const float*)d_in[7];
    const float* b2  = (const float*)d_in[8];
    const float* g1  = (const float*)d_in[9];
    const float* be1 = (const float*)d_in[10];
    const float* g2  = (const float*)d_in[11];
    const float* be2 = (const float*)d_in[12];

    char* ws = (char*)d_ws;
    const size_t M8 = 8388608;  // 8 MiB
    uint16_t* WqkT = (uint16_t*)(ws + 0 * M8);   // [8192][1024]: WqT then WkT
    uint16_t* WqT  = WqkT;                        // [4096][1024]
    uint16_t* WkT  = (uint16_t*)(ws + 1 * M8);
    uint16_t* WvT  = (uint16_t*)(ws + 2 * M8);
    uint16_t* WoT  = (uint16_t*)(ws + 3 * M8);   // [1024][4096]
    uint16_t* W1T  = (uint16_t*)(ws + 4 * M8);
    uint16_t* W2T  = (uint16_t*)(ws + 5 * M8);   // [1024][4096]
    uint16_t* x1   = (uint16_t*)(ws + 6 * M8);   // [4096][1024]
    uint16_t* x2   = (uint16_t*)(ws + 7 * M8);
    uint16_t* QK   = (uint16_t*)(ws + 8 * M8);   // [4096][8192] (Q | K)
    uint16_t* Vt   = (uint16_t*)(ws + 16 * M8);  // [hd][tok]
    uint16_t* ctx  = (uint16_t*)(ws + 20 * M8);
    float*    xmid = (float*)(ws + 12 * M8);     // reuse QK upper (dead after attn)
    uint16_t* Hn   = (uint16_t*)(ws + 8 * M8);   // reuse QK lower (dead after attn)

    // weight convert+transpose (single launch, 6 weights)
    wconv6<<<dim3(128, 32, 6), 256, 0, stream>>>(Wq, Wk, Wv, W1, Wo, W2,
                                                 WqT, WkT, WvT, W1T, WoT, W2T);

    // pre-norm 1
    ln_bf16<<<4096, 256, 0, stream>>>(x, g1, be1, x1);

    // merged Q|K projection + V^T projection (256^2 counted-vmcnt pipeline)
    gemm256<0><<<512, 512, 0, stream>>>(x1, WqkT, QK, nullptr, 4096, 8192, 1024);
    gemm256<0><<<256, 512, 0, stream>>>(WvT, x1, Vt, nullptr, 4096, 4096, 1024);

    // attention (512 blocks x 256 threads, 32 q-rows/wave)
    attn<<<512, 256, 0, stream>>>(QK, QK + 4096, Vt, ctx);

    // Wo projection + residual -> xmid (fp32), 128^2 BK=64 pipeline
    gemm128p<3><<<256, 256, 0, stream>>>(ctx, WoT, xmid, nullptr, x, 4096, 1024, 4096);

    // pre-norm 2
    ln_bf16<<<4096, 256, 0, stream>>>(xmid, g2, be2, x2);

    // FFN
    gemm256<1><<<256, 512, 0, stream>>>(x2, W1T, Hn, b1, 4096, 4096, 1024);
    gemm128p<2><<<256, 256, 0, stream>>>(Hn, W2T, (float*)d_out, b2, xmid, 4096, 1024, 4096);
}